// Round 1
// baseline (389.207 us; speedup 1.0000x reference)
//
#include <hip/hip_runtime.h>
#include <math.h>

#define S_LEN 2048
#define BSZ 2
#define DM 512
#define NH 8
#define HD 64
#define RTOT (S_LEN*BSZ)       // 4096 rows, row r = s*BSZ + b
#define T_KEEP 32              // last 32 positions are the only nonzero attn rows
#define ROW0 ((S_LEN - T_KEEP)*BSZ)  // 4032

// ---------------- Kernel 1: fused q/k/v projection + sigma accumulation --------
// grid (RTOT/TM, NH), block 256. Computes for its 64 rows and head h the
// 64-col slices of q,k,v (= 64x192 tile GEMM over K=512), then
// sig = sigmoid((q.k)/(8 e^beta)) per row, accumulates kbar += sig*k,
// vbar += sig*v into global via atomics.
#define TM 64
#define TN 192
#define BK 32
#define PAD 36   // multiple of 4 (float4 LDS stores) ; 36%32=4 -> <=2-way conflicts (free)

__global__ __launch_bounds__(256) void proj_accum(
    const float* __restrict__ x,
    const float* __restrict__ Wq, const float* __restrict__ bq,
    const float* __restrict__ Wk, const float* __restrict__ bk,
    const float* __restrict__ Wv, const float* __restrict__ bv,
    const float* __restrict__ beta,
    float* __restrict__ gbar)   // [0..1024) kbar[z][j], [1024..2048) vbar[z][j]
{
    __shared__ float smem[TM*TN];   // used as tiles (9216 f) during K loop, then as C (12288 f)
    __shared__ float sb[256];       // per-block partial kbar/vbar: [b][k|v][64]

    const int tid = threadIdx.x;
    const int h  = blockIdx.y;
    const int r0 = blockIdx.x * TM;
    const int tx = tid & 15;        // col group
    const int ty = tid >> 4;        // row group

    float acc[4][12];
    #pragma unroll
    for (int r = 0; r < 4; ++r)
        #pragma unroll
        for (int c = 0; c < 12; ++c) acc[r][c] = 0.f;

    for (int k0 = 0; k0 < DM; k0 += BK) {
        // load X tile: 64 rows x 32 cols (512 float4, 2 per thread)
        #pragma unroll
        for (int l = tid; l < TM*(BK/4); l += 256) {
            int row = l >> 3;
            int q4  = l & 7;
            float4 xv = *(const float4*)&x[(size_t)(r0+row)*DM + k0 + q4*4];
            *(float4*)&smem[row*PAD + q4*4] = xv;
        }
        // load W tile: 192 rows (q|k|v x 64) x 32 cols (1536 float4, 6 per thread)
        #pragma unroll
        for (int l = tid; l < TN*(BK/4); l += 256) {
            int row = l >> 3;          // 0..191
            int q4  = l & 7;
            int m   = row >> 6;        // 0=q,1=k,2=v
            int cc  = row & 63;
            const float* W = (m == 0 ? Wq : (m == 1 ? Wk : Wv));
            float4 wv = *(const float4*)&W[(size_t)(h*HD + cc)*DM + k0 + q4*4];
            *(float4*)&smem[TM*PAD + row*PAD + q4*4] = wv;
        }
        __syncthreads();
        #pragma unroll
        for (int kk = 0; kk < BK; ++kk) {
            float a[4], b[12];
            #pragma unroll
            for (int r = 0; r < 4; ++r) a[r] = smem[(ty + 16*r)*PAD + kk];
            #pragma unroll
            for (int c = 0; c < 12; ++c) b[c] = smem[TM*PAD + (tx + 16*c)*PAD + kk];
            #pragma unroll
            for (int r = 0; r < 4; ++r)
                #pragma unroll
                for (int c = 0; c < 12; ++c) acc[r][c] += a[r]*b[c];
        }
        __syncthreads();
    }

    // dump C (+bias) to LDS, zero the partial buffer
    sb[tid] = 0.f;
    #pragma unroll
    for (int r = 0; r < 4; ++r) {
        #pragma unroll
        for (int c = 0; c < 12; ++c) {
            int col = tx + 16*c;
            int m  = col >> 6;
            int cc = col & 63;
            float bias = (m == 0 ? bq : (m == 1 ? bk : bv))[h*HD + cc];
            smem[(ty + 16*r)*TN + col] = acc[r][c] + bias;
        }
    }
    __syncthreads();

    // epilogue: per row i, score = q.k ; sig = sigmoid(score/(8 e^beta));
    // accumulate sig*k, sig*v per (b, j)
    const int lane = tid & 63;
    const int wv   = tid >> 6;  // wave 0..3
    const float inv_scale = 1.0f / (8.0f * expf(beta[h]));
    float kacc0 = 0.f, kacc1 = 0.f, vacc0 = 0.f, vacc1 = 0.f;
    for (int i = wv; i < TM; i += 4) {
        float qv = smem[i*TN + lane];
        float kv = smem[i*TN + 64 + lane];
        float vv = smem[i*TN + 128 + lane];
        float p = qv * kv;
        #pragma unroll
        for (int off = 32; off > 0; off >>= 1) p += __shfl_xor(p, off, 64);
        float sig = 1.0f / (1.0f + expf(-p * inv_scale));
        if (((r0 + i) & 1) == 0) { kacc0 += sig*kv; vacc0 += sig*vv; }
        else                     { kacc1 += sig*kv; vacc1 += sig*vv; }
    }
    atomicAdd(&sb[  0 + lane], kacc0);  // b=0, kbar
    atomicAdd(&sb[ 64 + lane], vacc0);  // b=0, vbar
    atomicAdd(&sb[128 + lane], kacc1);  // b=1, kbar
    atomicAdd(&sb[192 + lane], vacc1);  // b=1, vbar
    __syncthreads();
    {
        int b   = tid >> 7;
        int sel = (tid >> 6) & 1;   // 0=kbar, 1=vbar
        int j   = tid & 63;
        int z   = b*NH + h;
        atomicAdd(&gbar[sel*1024 + z*64 + j], sb[tid]);
    }
}

// ---------------- Kernel 2: per-z window softmax + attn rows -------------------
// grid 16 (z = b*8+h), block 256. Recomputes the 32 needed q rows, computes
// p_wi = softmax_with_sink(q_{wi*64+63} . kbar / (8 e^beta)), writes
// acat[(wi*2+b)*512 + h*64 + j] = (p_wi + (wi==31)) * vbar[z][j].
__global__ __launch_bounds__(256) void finalize(
    const float* __restrict__ x, const float* __restrict__ Wq,
    const float* __restrict__ bq, const float* __restrict__ beta,
    const float* __restrict__ gbar, float* __restrict__ acat)
{
    const int z = blockIdx.x;
    const int b = z / NH;
    const int h = z % NH;
    const int tid = threadIdx.x;
    const int lane = tid & 63;
    const int wg = tid >> 6;

    __shared__ float s_sc[T_KEEP];
    __shared__ float s_c[T_KEEP];

    const float kb = gbar[z*64 + lane];
    const float vb = gbar[1024 + z*64 + lane];
    const float inv_scale = 1.0f / (8.0f * expf(beta[h]));
    const float* wqrow = &Wq[(size_t)(h*HD + lane)*DM];
    const float bias = bq[h*HD + lane];

    #pragma unroll
    for (int m = 0; m < 8; ++m) {
        int wi = wg*8 + m;
        int r  = (wi*64 + 63)*BSZ + b;
        const float* xr = &x[(size_t)r*DM];
        float qv = bias;
        for (int k = 0; k < DM; k += 4) {
            float4 xv = *(const float4*)&xr[k];
            float4 w4 = *(const float4*)&wqrow[k];
            qv += xv.x*w4.x + xv.y*w4.y + xv.z*w4.z + xv.w*w4.w;
        }
        float p = qv * kb;
        #pragma unroll
        for (int off = 32; off > 0; off >>= 1) p += __shfl_xor(p, off, 64);
        if (lane == 0) s_sc[wi] = p * inv_scale;
    }
    __syncthreads();
    if (tid == 0) {
        float mx = 0.f;  // sink score is 0
        for (int wi = 0; wi < T_KEEP; ++wi) mx = fmaxf(mx, s_sc[wi]);
        float denom = expf(-mx);  // sink
        for (int wi = 0; wi < T_KEEP; ++wi) denom += expf(s_sc[wi] - mx);
        for (int wi = 0; wi < T_KEEP; ++wi) {
            float c = expf(s_sc[wi] - mx) / denom;
            if (wi == T_KEEP-1) c += 1.0f;   // iter-0 contribution at t = s-1
            s_c[wi] = c;
        }
    }
    __syncthreads();
    #pragma unroll
    for (int m = 0; m < 8; ++m) {
        int wi = wg*8 + m;
        acat[(size_t)(wi*BSZ + b)*DM + h*HD + lane] = s_c[wi] * vb;
    }
}

// ---------------- Kernel 3: output fill + small GEMM ---------------------------
// grid RTOT (one block per output row), block 256.
// rows < ROW0: out = bo ; rows >= ROW0: out = acat_row @ Wo.T + bo
__global__ __launch_bounds__(256) void write_out(
    const float* __restrict__ acat, const float* __restrict__ Wo,
    const float* __restrict__ bo, float* __restrict__ out)
{
    const int r = blockIdx.x;
    const int tid = threadIdx.x;
    if (r < ROW0) {
        for (int c = tid; c < DM; c += 256) out[(size_t)r*DM + c] = bo[c];
    } else {
        __shared__ float arow[DM];
        const float* src = &acat[(size_t)(r - ROW0)*DM];
        for (int c = tid; c < DM; c += 256) arow[c] = src[c];
        __syncthreads();
        for (int c = tid; c < DM; c += 256) {
            const float* worow = &Wo[(size_t)c*DM];
            float a = bo[c];
            for (int k = 0; k < DM; k += 4) {
                float4 a4 = *(const float4*)&arow[k];
                float4 w4 = *(const float4*)&worow[k];
                a += a4.x*w4.x + a4.y*w4.y + a4.z*w4.z + a4.w*w4.w;
            }
            out[(size_t)r*DM + c] = a;
        }
    }
}

extern "C" void kernel_launch(void* const* d_in, const int* in_sizes, int n_in,
                              void* d_out, int out_size, void* d_ws, size_t ws_size,
                              hipStream_t stream) {
    const float* x    = (const float*)d_in[0];
    const float* Wq   = (const float*)d_in[1];
    const float* bq   = (const float*)d_in[2];
    const float* Wk   = (const float*)d_in[3];
    const float* bk   = (const float*)d_in[4];
    const float* Wv   = (const float*)d_in[5];
    const float* bv   = (const float*)d_in[6];
    const float* Wo   = (const float*)d_in[7];
    const float* bo   = (const float*)d_in[8];
    const float* beta = (const float*)d_in[9];
    float* ws   = (float*)d_ws;
    float* gbar = ws;            // 2048 floats (kbar | vbar)
    float* acat = ws + 2048;     // 64*512 floats

    hipMemsetAsync(gbar, 0, 2048*sizeof(float), stream);
    dim3 g1(RTOT/TM, NH);
    proj_accum<<<g1, 256, 0, stream>>>(x, Wq, bq, Wk, bk, Wv, bv, beta, gbar);
    finalize<<<16, 256, 0, stream>>>(x, Wq, bq, beta, gbar, acat);
    write_out<<<RTOT, 256, 0, stream>>>(acat, Wo, bo, (float*)d_out);
}

// Round 2
// 255.599 us; speedup vs baseline: 1.5227x; 1.5227x over previous
//
#include <hip/hip_runtime.h>
#include <math.h>

#define S_LEN 2048
#define BSZ 2
#define DM 512
#define NH 8
#define HD 64
#define RTOT (S_LEN*BSZ)       // 4096 rows, row r = s*BSZ + b
#define T_KEEP 32              // last 32 positions are the only nonzero attn rows
#define ROW0 ((S_LEN - T_KEEP)*BSZ)  // 4032

// ---------------- Kernel 1: fused q/k/v projection + sigma accumulation --------
// grid (RTOT/TM, NH), block 256. Computes for its 64 rows and head h the
// 64-col slices of q,k,v (= 64x192 tile GEMM over K=512), then
// sig = sigmoid((q.k)/(8 e^beta)) per row, accumulates kbar += sig*k,
// vbar += sig*v into global via atomics. Also spills q rows with s%64==63
// (the only q rows the window softmax needs) to qsel.
#define TM 64
#define TN 192
#define BK 32
#define PAD 36   // multiple of 4 (float4 LDS ops); tx-stride 36%32=4 banks -> 2-way (free)

__global__ __launch_bounds__(256) void proj_accum(
    const float* __restrict__ x,
    const float* __restrict__ Wq, const float* __restrict__ bq,
    const float* __restrict__ Wk, const float* __restrict__ bk,
    const float* __restrict__ Wv, const float* __restrict__ bv,
    const float* __restrict__ beta,
    float* __restrict__ gbar,   // [0..1024) kbar[z][j], [1024..2048) vbar[z][j]
    float* __restrict__ qsel)   // [z][wi][64]
{
    __shared__ float smem[TM*TN];   // tiles (PAD layout) during K loop, then C (dense)
    __shared__ float sb[256];       // per-block partial kbar/vbar: [b][k|v][64]

    const int tid = threadIdx.x;
    const int h  = blockIdx.y;
    const int r0 = blockIdx.x * TM;
    const int tx = tid & 15;        // col group
    const int ty = tid >> 4;        // row group

    float acc[4][12];
    #pragma unroll
    for (int r = 0; r < 4; ++r)
        #pragma unroll
        for (int c = 0; c < 12; ++c) acc[r][c] = 0.f;

    for (int k0 = 0; k0 < DM; k0 += BK) {
        // load X tile: 64 rows x 32 cols (512 float4, 2 per thread)
        #pragma unroll
        for (int l = tid; l < TM*(BK/4); l += 256) {
            int row = l >> 3;
            int q4  = l & 7;
            float4 xv = *(const float4*)&x[(size_t)(r0+row)*DM + k0 + q4*4];
            *(float4*)&smem[row*PAD + q4*4] = xv;
        }
        // load W tile: 192 rows (q|k|v x 64) x 32 cols (1536 float4, 6 per thread)
        #pragma unroll
        for (int l = tid; l < TN*(BK/4); l += 256) {
            int row = l >> 3;          // 0..191
            int q4  = l & 7;
            int m   = row >> 6;        // 0=q,1=k,2=v
            int cc  = row & 63;
            const float* W = (m == 0 ? Wq : (m == 1 ? Wk : Wv));
            float4 wv = *(const float4*)&W[(size_t)(h*HD + cc)*DM + k0 + q4*4];
            *(float4*)&smem[TM*PAD + row*PAD + q4*4] = wv;
        }
        __syncthreads();
        #pragma unroll
        for (int kk = 0; kk < BK; kk += 4) {
            float4 a4[4], b4[12];
            #pragma unroll
            for (int r = 0; r < 4; ++r)
                a4[r] = *(const float4*)&smem[(ty + 16*r)*PAD + kk];
            #pragma unroll
            for (int c = 0; c < 12; ++c)
                b4[c] = *(const float4*)&smem[TM*PAD + (tx + 16*c)*PAD + kk];
            #pragma unroll
            for (int r = 0; r < 4; ++r)
                #pragma unroll
                for (int c = 0; c < 12; ++c) {
                    acc[r][c] += a4[r].x*b4[c].x;
                    acc[r][c] += a4[r].y*b4[c].y;
                    acc[r][c] += a4[r].z*b4[c].z;
                    acc[r][c] += a4[r].w*b4[c].w;
                }
        }
        __syncthreads();
    }

    // dump C (+bias) to LDS, zero the partial buffer
    sb[tid] = 0.f;
    #pragma unroll
    for (int r = 0; r < 4; ++r) {
        #pragma unroll
        for (int c = 0; c < 12; ++c) {
            int col = tx + 16*c;
            int m  = col >> 6;
            int cc = col & 63;
            float bias = (m == 0 ? bq : (m == 1 ? bk : bv))[h*HD + cc];
            smem[(ty + 16*r)*TN + col] = acc[r][c] + bias;
        }
    }
    __syncthreads();

    // epilogue: per row i, score = q.k ; sig = sigmoid(score/(8 e^beta));
    // accumulate sig*k, sig*v per (b, j); spill q rows with s%64==63
    const int lane = tid & 63;
    const int wv   = tid >> 6;  // wave 0..3
    const float inv_scale = 1.0f / (8.0f * expf(beta[h]));
    float kacc0 = 0.f, kacc1 = 0.f, vacc0 = 0.f, vacc1 = 0.f;
    for (int i = wv; i < TM; i += 4) {
        float qv = smem[i*TN + lane];
        float kv = smem[i*TN + 64 + lane];
        float vv = smem[i*TN + 128 + lane];
        int r = r0 + i;
        int s = r >> 1;   // BSZ=2
        int b = r & 1;
        if ((s & 63) == 63) {
            int wi = s >> 6;
            qsel[((size_t)(b*NH + h)*T_KEEP + wi)*64 + lane] = qv;
        }
        float p = qv * kv;
        #pragma unroll
        for (int off = 32; off > 0; off >>= 1) p += __shfl_xor(p, off, 64);
        float sig = 1.0f / (1.0f + expf(-p * inv_scale));
        if (b == 0) { kacc0 += sig*kv; vacc0 += sig*vv; }
        else        { kacc1 += sig*kv; vacc1 += sig*vv; }
    }
    atomicAdd(&sb[  0 + lane], kacc0);  // b=0, kbar
    atomicAdd(&sb[ 64 + lane], vacc0);  // b=0, vbar
    atomicAdd(&sb[128 + lane], kacc1);  // b=1, kbar
    atomicAdd(&sb[192 + lane], vacc1);  // b=1, vbar
    __syncthreads();
    {
        int b   = tid >> 7;
        int sel = (tid >> 6) & 1;   // 0=kbar, 1=vbar
        int j   = tid & 63;
        int z   = b*NH + h;
        atomicAdd(&gbar[sel*1024 + z*64 + j], sb[tid]);
    }
}

// ---------------- Kernel 2: per-z window softmax + attn rows -------------------
// grid 16 (z = b*8+h), block 256. Reads precomputed q rows (qsel), computes
// p_wi = softmax_with_sink(qsel[wi] . kbar / (8 e^beta)), writes
// acat[(wi*2+b)*512 + h*64 + j] = (p_wi + (wi==31)) * vbar[z][j].
__global__ __launch_bounds__(256) void finalize(
    const float* __restrict__ qsel, const float* __restrict__ beta,
    const float* __restrict__ gbar, float* __restrict__ acat)
{
    const int z = blockIdx.x;
    const int b = z / NH;
    const int h = z % NH;
    const int tid = threadIdx.x;
    const int lane = tid & 63;
    const int wg = tid >> 6;

    __shared__ float s_sc[T_KEEP];
    __shared__ float s_c[T_KEEP];

    const float kb = gbar[z*64 + lane];
    const float vb = gbar[1024 + z*64 + lane];
    const float inv_scale = 1.0f / (8.0f * expf(beta[h]));

    #pragma unroll
    for (int m = 0; m < 8; ++m) {
        int wi = wg*8 + m;
        float p = qsel[((size_t)z*T_KEEP + wi)*64 + lane] * kb;
        #pragma unroll
        for (int off = 32; off > 0; off >>= 1) p += __shfl_xor(p, off, 64);
        if (lane == 0) s_sc[wi] = p * inv_scale;
    }
    __syncthreads();
    if (tid == 0) {
        float mx = 0.f;  // sink score is 0
        for (int wi = 0; wi < T_KEEP; ++wi) mx = fmaxf(mx, s_sc[wi]);
        float denom = expf(-mx);  // sink
        for (int wi = 0; wi < T_KEEP; ++wi) denom += expf(s_sc[wi] - mx);
        for (int wi = 0; wi < T_KEEP; ++wi) {
            float c = expf(s_sc[wi] - mx) / denom;
            if (wi == T_KEEP-1) c += 1.0f;   // iter-0 contribution at t = s-1
            s_c[wi] = c;
        }
    }
    __syncthreads();
    #pragma unroll
    for (int m = 0; m < 8; ++m) {
        int wi = wg*8 + m;
        acat[(size_t)(wi*BSZ + b)*DM + h*HD + lane] = s_c[wi] * vb;
    }
}

// ---------------- Kernel 3: output fill + small GEMM ---------------------------
// grid RTOT (one block per output row), block 256.
// rows < ROW0: out = bo ; rows >= ROW0: out = acat_row @ Wo.T + bo
__global__ __launch_bounds__(256) void write_out(
    const float* __restrict__ acat, const float* __restrict__ Wo,
    const float* __restrict__ bo, float* __restrict__ out)
{
    const int r = blockIdx.x;
    const int tid = threadIdx.x;
    if (r < ROW0) {
        for (int c = tid; c < DM; c += 256) out[(size_t)r*DM + c] = bo[c];
    } else {
        __shared__ float arow[DM];
        const float* src = &acat[(size_t)(r - ROW0)*DM];
        for (int c = tid; c < DM; c += 256) arow[c] = src[c];
        __syncthreads();
        for (int c = tid; c < DM; c += 256) {
            const float* worow = &Wo[(size_t)c*DM];
            float a = bo[c];
            for (int k = 0; k < DM; k += 4) {
                float4 a4 = *(const float4*)&arow[k];
                float4 w4 = *(const float4*)&worow[k];
                a += a4.x*w4.x + a4.y*w4.y + a4.z*w4.z + a4.w*w4.w;
            }
            out[(size_t)r*DM + c] = a;
        }
    }
}

extern "C" void kernel_launch(void* const* d_in, const int* in_sizes, int n_in,
                              void* d_out, int out_size, void* d_ws, size_t ws_size,
                              hipStream_t stream) {
    const float* x    = (const float*)d_in[0];
    const float* Wq   = (const float*)d_in[1];
    const float* bq   = (const float*)d_in[2];
    const float* Wk   = (const float*)d_in[3];
    const float* bk   = (const float*)d_in[4];
    const float* Wv   = (const float*)d_in[5];
    const float* bv   = (const float*)d_in[6];
    const float* Wo   = (const float*)d_in[7];
    const float* bo   = (const float*)d_in[8];
    const float* beta = (const float*)d_in[9];
    float* ws   = (float*)d_ws;
    float* gbar = ws;            // 2048 floats (kbar | vbar)
    float* acat = ws + 2048;     // 64*512 floats
    float* qsel = ws + 2048 + 64*512;  // 16*32*64 floats

    hipMemsetAsync(gbar, 0, 2048*sizeof(float), stream);
    dim3 g1(RTOT/TM, NH);
    proj_accum<<<g1, 256, 0, stream>>>(x, Wq, bq, Wk, bk, Wv, bv, beta, gbar, qsel);
    finalize<<<16, 256, 0, stream>>>(qsel, beta, gbar, acat);
    write_out<<<RTOT, 256, 0, stream>>>(acat, Wo, bo, (float*)d_out);
}

// Round 3
// 168.704 us; speedup vs baseline: 2.3070x; 1.5151x over previous
//
#include <hip/hip_runtime.h>
#include <hip/hip_bf16.h>
#include <math.h>

#define S_LEN 2048
#define BSZ 2
#define DM 512
#define NH 8
#define HD 64
#define RTOT (S_LEN*BSZ)             // 4096 rows, row r = s*BSZ + b
#define T_KEEP 32
#define ROW0 ((S_LEN - T_KEEP)*BSZ)  // 4032
#define NXELEM (RTOT*DM)             // 2097152
#define NWROW  (NH*192)              // 1536 (per-head q|k|v row blocks)
#define NWELEM (NWROW*DM)            // 786432

typedef __attribute__((ext_vector_type(8))) short short8;
typedef __attribute__((ext_vector_type(4))) float floatx4;

__device__ __forceinline__ void gld16(const void* g, void* l) {
    __builtin_amdgcn_global_load_lds((const __attribute__((address_space(1))) void*)g,
                                     (__attribute__((address_space(3))) void*)l, 16, 0, 0);
}

__device__ __forceinline__ void cvt2(float v, short& hs, short& ls) {
    __hip_bfloat16 h = __float2bfloat16(v);
    float hf = __bfloat162float(h);
    __hip_bfloat16 l = __float2bfloat16(v - hf);
    hs = __builtin_bit_cast(short, h);
    ls = __builtin_bit_cast(short, l);
}

// ------------- Kernel 0: fp32 -> bf16 hi/lo planes + bias concat ---------------
// wb row layout: R = h*192 + m*64 + c  (m: 0=q,1=k,2=v), K contiguous.
__global__ __launch_bounds__(256) void convert(
    const float* __restrict__ x,
    const float* __restrict__ Wq, const float* __restrict__ Wk, const float* __restrict__ Wv,
    const float* __restrict__ bq, const float* __restrict__ bk, const float* __restrict__ bv,
    short* __restrict__ xh, short* __restrict__ xl,
    short* __restrict__ wh, short* __restrict__ wl, float* __restrict__ bcat)
{
    const int g = blockIdx.x*blockDim.x + threadIdx.x;
    const int stride = gridDim.x*blockDim.x;
    const int total4 = (NXELEM + NWELEM)/4;
    for (int i = g; i < total4; i += stride) {
        float4 v; size_t dst;
        short* dh; short* dl;
        if (i < NXELEM/4) {
            v = ((const float4*)x)[i];
            dst = (size_t)i*4; dh = xh; dl = xl;
        } else {
            int j = i - NXELEM/4;
            int e = j*4;
            int R = e >> 9;           // wb row
            int k = e & 511;
            int hh = R / 192; int rem = R - hh*192; int m = rem >> 6; int c = rem & 63;
            const float* W = (m == 0 ? Wq : (m == 1 ? Wk : Wv));
            v = *(const float4*)&W[(size_t)(hh*HD + c)*DM + k];
            dst = (size_t)R*DM + k; dh = wh; dl = wl;
        }
        short4 hv, lv;
        cvt2(v.x, hv.x, lv.x); cvt2(v.y, hv.y, lv.y);
        cvt2(v.z, hv.z, lv.z); cvt2(v.w, hv.w, lv.w);
        *(short4*)&dh[dst] = hv;
        *(short4*)&dl[dst] = lv;
    }
    if (g < NWROW) {
        int hh = g / 192, rem = g - hh*192, m = rem >> 6, c = rem & 63;
        bcat[g] = (m == 0 ? bq : (m == 1 ? bk : bv))[hh*HD + c];
    }
}

// ------------- Kernel 1: MFMA split-bf16 qkv GEMM + sigma accumulation ---------
// grid (32, 8): block = rows [r0, r0+128) x head h's 192 cols (q|k|v).
// Split product: C = xh*wh^T + xl*wh^T + xh*wl^T  (~fp32 accuracy).
// LDS stage (fragment-ordered, 16B/lane): A_hi[8x1KB] A_lo[8x1KB] B_hi[12x1KB] B_lo[12x1KB]
#define A_HI 0
#define A_LO 8192
#define B_HI 16384
#define B_LO 28672

__global__ __launch_bounds__(256) void qkv_gemm(
    const short* __restrict__ xh, const short* __restrict__ xl,
    const short* __restrict__ wh, const short* __restrict__ wl,
    const float* __restrict__ bcat, const float* __restrict__ beta,
    float* __restrict__ gbar, float* __restrict__ qsel)
{
    __shared__ __align__(16) char smem[49152];   // stage (40KB) then C dump (48KB)
    __shared__ float sb[256];

    const int tid  = threadIdx.x;
    const int w    = tid >> 6;
    const int lane = tid & 63;
    const int lrow = lane & 15;
    const int lk8  = lane >> 4;
    const int h    = blockIdx.y;
    const int r0   = blockIdx.x * 128;

    floatx4 acc[2][12];
    #pragma unroll
    for (int i = 0; i < 2; ++i)
        #pragma unroll
        for (int j = 0; j < 12; ++j) acc[i][j] = (floatx4)0.f;

    // global per-lane source pointers (advance by 32 shorts per chunk)
    const short* pA0h = xh + (size_t)(r0 + 2*w*16 + lrow)*DM + lk8*8;
    const short* pA1h = pA0h + 16*DM;
    const short* pA0l = xl + (size_t)(r0 + 2*w*16 + lrow)*DM + lk8*8;
    const short* pA1l = pA0l + 16*DM;
    const short* pB0h = wh + (size_t)(h*192 + 3*w*16 + lrow)*DM + lk8*8;
    const short* pB1h = pB0h + 16*DM;
    const short* pB2h = pB0h + 32*DM;
    const short* pB0l = wl + (size_t)(h*192 + 3*w*16 + lrow)*DM + lk8*8;
    const short* pB1l = pB0l + 16*DM;
    const short* pB2l = pB0l + 32*DM;
    // wave-uniform LDS dests
    char* sA0h = smem + A_HI + (2*w+0)*1024;
    char* sA1h = smem + A_HI + (2*w+1)*1024;
    char* sA0l = smem + A_LO + (2*w+0)*1024;
    char* sA1l = smem + A_LO + (2*w+1)*1024;
    char* sB0h = smem + B_HI + (3*w+0)*1024;
    char* sB1h = smem + B_HI + (3*w+1)*1024;
    char* sB2h = smem + B_HI + (3*w+2)*1024;
    char* sB0l = smem + B_LO + (3*w+0)*1024;
    char* sB1l = smem + B_LO + (3*w+1)*1024;
    char* sB2l = smem + B_LO + (3*w+2)*1024;

    for (int kc = 0; kc < 16; ++kc) {
        const int ko = kc*32;
        gld16(pA0h + ko, sA0h); gld16(pA1h + ko, sA1h);
        gld16(pA0l + ko, sA0l); gld16(pA1l + ko, sA1l);
        gld16(pB0h + ko, sB0h); gld16(pB1h + ko, sB1h); gld16(pB2h + ko, sB2h);
        gld16(pB0l + ko, sB0l); gld16(pB1l + ko, sB1l); gld16(pB2l + ko, sB2l);
        __syncthreads();
        short8 a0h = *(const short8*)(smem + A_HI + (2*w+0)*1024 + lane*16);
        short8 a1h = *(const short8*)(smem + A_HI + (2*w+1)*1024 + lane*16);
        short8 a0l = *(const short8*)(smem + A_LO + (2*w+0)*1024 + lane*16);
        short8 a1l = *(const short8*)(smem + A_LO + (2*w+1)*1024 + lane*16);
        #pragma unroll
        for (int j = 0; j < 12; ++j) {
            short8 bh = *(const short8*)(smem + B_HI + j*1024 + lane*16);
            short8 bl = *(const short8*)(smem + B_LO + j*1024 + lane*16);
            acc[0][j] = __builtin_amdgcn_mfma_f32_16x16x32_bf16(a0h, bh, acc[0][j], 0, 0, 0);
            acc[1][j] = __builtin_amdgcn_mfma_f32_16x16x32_bf16(a1h, bh, acc[1][j], 0, 0, 0);
            acc[0][j] = __builtin_amdgcn_mfma_f32_16x16x32_bf16(a0l, bh, acc[0][j], 0, 0, 0);
            acc[1][j] = __builtin_amdgcn_mfma_f32_16x16x32_bf16(a1l, bh, acc[1][j], 0, 0, 0);
            acc[0][j] = __builtin_amdgcn_mfma_f32_16x16x32_bf16(a0h, bl, acc[0][j], 0, 0, 0);
            acc[1][j] = __builtin_amdgcn_mfma_f32_16x16x32_bf16(a1h, bl, acc[1][j], 0, 0, 0);
        }
        __syncthreads();
    }

    // bias per col-tile (col = j*16 + lrow)
    float bias[12];
    #pragma unroll
    for (int j = 0; j < 12; ++j) bias[j] = bcat[h*192 + j*16 + lrow];

    const float inv_scale = 1.0f / (8.0f * expf(beta[h]));
    float* Cl = (float*)smem;
    float kacc0 = 0.f, kacc1 = 0.f, vacc0 = 0.f, vacc1 = 0.f;
    sb[tid] = 0.f;

    #pragma unroll
    for (int half = 0; half < 2; ++half) {
        if ((w >> 1) == half) {
            #pragma unroll
            for (int i = 0; i < 2; ++i)
                #pragma unroll
                for (int j = 0; j < 12; ++j)
                    #pragma unroll
                    for (int reg = 0; reg < 4; ++reg) {
                        int rl = (w & 1)*32 + i*16 + lk8*4 + reg;     // 0..63
                        Cl[rl*192 + j*16 + lrow] = acc[i][j][reg] + bias[j];
                    }
        }
        __syncthreads();
        for (int i2 = w; i2 < 64; i2 += 4) {
            float qv = Cl[i2*192 + lane];
            float kv = Cl[i2*192 + 64 + lane];
            float vv = Cl[i2*192 + 128 + lane];
            int r = r0 + half*64 + i2;
            int s = r >> 1;
            int b = r & 1;
            if ((s & 63) == 63) {
                int wi = s >> 6;
                qsel[((size_t)(b*NH + h)*T_KEEP + wi)*64 + lane] = qv;
            }
            float p = qv * kv;
            #pragma unroll
            for (int off = 32; off > 0; off >>= 1) p += __shfl_xor(p, off, 64);
            float sig = 1.0f / (1.0f + expf(-p * inv_scale));
            if (b == 0) { kacc0 += sig*kv; vacc0 += sig*vv; }
            else        { kacc1 += sig*kv; vacc1 += sig*vv; }
        }
        __syncthreads();
    }

    atomicAdd(&sb[  0 + lane], kacc0);
    atomicAdd(&sb[ 64 + lane], vacc0);
    atomicAdd(&sb[128 + lane], kacc1);
    atomicAdd(&sb[192 + lane], vacc1);
    __syncthreads();
    {
        int b   = tid >> 7;
        int sel = (tid >> 6) & 1;
        int j   = tid & 63;
        int z   = b*NH + h;
        atomicAdd(&gbar[sel*1024 + z*64 + j], sb[tid]);
    }
}

// ------------- Kernel 2: per-z window softmax -> acat --------------------------
__global__ __launch_bounds__(256) void finalize(
    const float* __restrict__ qsel, const float* __restrict__ beta,
    const float* __restrict__ gbar, float* __restrict__ acat)
{
    const int z = blockIdx.x;
    const int b = z / NH;
    const int h = z % NH;
    const int tid = threadIdx.x;
    const int lane = tid & 63;
    const int wg = tid >> 6;

    __shared__ float s_sc[T_KEEP];
    __shared__ float s_c[T_KEEP];

    const float kb = gbar[z*64 + lane];
    const float vb = gbar[1024 + z*64 + lane];
    const float inv_scale = 1.0f / (8.0f * expf(beta[h]));

    #pragma unroll
    for (int m = 0; m < 8; ++m) {
        int wi = wg*8 + m;
        float p = qsel[((size_t)z*T_KEEP + wi)*64 + lane] * kb;
        #pragma unroll
        for (int off = 32; off > 0; off >>= 1) p += __shfl_xor(p, off, 64);
        if (lane == 0) s_sc[wi] = p * inv_scale;
    }
    __syncthreads();
    if (tid == 0) {
        float mx = 0.f;  // sink score is 0
        for (int wi = 0; wi < T_KEEP; ++wi) mx = fmaxf(mx, s_sc[wi]);
        float denom = expf(-mx);
        for (int wi = 0; wi < T_KEEP; ++wi) denom += expf(s_sc[wi] - mx);
        for (int wi = 0; wi < T_KEEP; ++wi) {
            float c = expf(s_sc[wi] - mx) / denom;
            if (wi == T_KEEP-1) c += 1.0f;
            s_c[wi] = c;
        }
    }
    __syncthreads();
    #pragma unroll
    for (int m = 0; m < 8; ++m) {
        int wi = wg*8 + m;
        acat[(size_t)(wi*BSZ + b)*DM + h*HD + lane] = s_c[wi] * vb;
    }
}

// ------------- Kernel 3: background fill (rows < ROW0 are just bo) -------------
__global__ __launch_bounds__(256) void out_fill(
    const float* __restrict__ bo, float* __restrict__ out)
{
    const int g = blockIdx.x*blockDim.x + threadIdx.x;
    const int stride = gridDim.x*blockDim.x;
    const int total4 = ROW0*DM/4;
    const float4* b4 = (const float4*)bo;
    float4* o4 = (float4*)out;
    for (int i = g; i < total4; i += stride) o4[i] = b4[i & 127];
}

// ------------- Kernel 4: last-64-rows output GEMM ------------------------------
__global__ __launch_bounds__(256) void ogemm(
    const float* __restrict__ acat, const float* __restrict__ Wo,
    const float* __restrict__ bo, float* __restrict__ out)
{
    const int r = ROW0 + blockIdx.x;
    const int tid = threadIdx.x;
    __shared__ float arow[DM];
    const float* src = &acat[(size_t)blockIdx.x*DM];
    for (int c = tid; c < DM; c += 256) arow[c] = src[c];
    __syncthreads();
    for (int c = tid; c < DM; c += 256) {
        const float* worow = &Wo[(size_t)c*DM];
        float a = bo[c];
        for (int k = 0; k < DM; k += 4) {
            float4 a4 = *(const float4*)&arow[k];
            float4 w4 = *(const float4*)&worow[k];
            a += a4.x*w4.x + a4.y*w4.y + a4.z*w4.z + a4.w*w4.w;
        }
        out[(size_t)r*DM + c] = a;
    }
}

extern "C" void kernel_launch(void* const* d_in, const int* in_sizes, int n_in,
                              void* d_out, int out_size, void* d_ws, size_t ws_size,
                              hipStream_t stream) {
    const float* x    = (const float*)d_in[0];
    const float* Wq   = (const float*)d_in[1];
    const float* bq   = (const float*)d_in[2];
    const float* Wk   = (const float*)d_in[3];
    const float* bk   = (const float*)d_in[4];
    const float* Wv   = (const float*)d_in[5];
    const float* bv   = (const float*)d_in[6];
    const float* Wo   = (const float*)d_in[7];
    const float* bo   = (const float*)d_in[8];
    const float* beta = (const float*)d_in[9];

    char* ws = (char*)d_ws;
    float* gbar = (float*)(ws + 0);           //   8 KB
    float* qsel = (float*)(ws + 8192);        // 128 KB
    float* acat = (float*)(ws + 139264);      // 128 KB
    float* bcat = (float*)(ws + 270336);      //   6 KB
    short* xh   = (short*)(ws + 276480);      //   4 MB
    short* xl   = (short*)(ws + 276480 + 4194304);
    short* wh   = (short*)(ws + 276480 + 2*4194304);
    short* wl   = (short*)(ws + 276480 + 2*4194304 + 1572864);

    hipMemsetAsync(gbar, 0, 2048*sizeof(float), stream);
    convert<<<1024, 256, 0, stream>>>(x, Wq, Wk, Wv, bq, bk, bv, xh, xl, wh, wl, bcat);
    dim3 g1(RTOT/128, NH);
    qkv_gemm<<<g1, 256, 0, stream>>>(xh, xl, wh, wl, bcat, beta, gbar, qsel);
    finalize<<<16, 256, 0, stream>>>(qsel, beta, gbar, acat);
    ogemm<<<64, 256, 0, stream>>>(acat, Wo, bo, (float*)d_out);
    out_fill<<<512, 256, 0, stream>>>(bo, (float*)d_out);
}